// Round 5
// baseline (597.272 us; speedup 1.0000x reference)
//
#include <hip/hip_runtime.h>

typedef _Float16 half8 __attribute__((ext_vector_type(8)));
typedef _Float16 half4 __attribute__((ext_vector_type(4)));
typedef float    floatx16 __attribute__((ext_vector_type(16)));

#define MFMA(a, b, c) __builtin_amdgcn_mfma_f32_32x32x16_f16((a), (b), (c), 0, 0, 0)

constexpr int NB = 32, NC = 256, NL = 1024, MI = 32, BJ = 32;
constexpr int NIT = NL / BJ;   // 32
constexpr int PSP = 33;

// LDS byte offsets (total 60032, launch_bounds(256,2) -> 2 blocks/CU)
constexpr int OFF_K    = 0;        // kF  f16 [16 ks][64 ls][8 t] = 16384
constexpr int OFF_V    = 16384;    // vF  f16 [8 ct][2 ksj][64 ls][8 t] = 16384 (swizzled granules)
constexpr int OFF_S    = 32768;    // sF  same = 16384
constexpr int OFF_PS   = 49152;    // pS  f32 [2 kh][32 i][33] = 8448
constexpr int OFF_PB   = 57600;    // pB  f16 [2 ksj][64 ls][8 t] = 2048
constexpr int OFF_ROWS = 59648;    // m/l/a rows 3*32*4 = 384
constexpr int SMEM_B   = 60032;

// Granule swizzle for vF/sF: XOR bits 5-6 of the granule index into bits 1-2 so the
// 4 jc-variants of one c-row land in different bank quads. Involution; write AND read.
__device__ __forceinline__ int swz(int g) { return g ^ (((g >> 5) & 3) << 1); }

// K staging: coalesced global reads (lanes sweep j), b128 frag writes.
__device__ __forceinline__ void stage_k(_Float16* kF, const float* kb, int tid) {
    #pragma unroll
    for (int r = 0; r < 4; ++r) {
        const int g = tid + r * 256, ks = g >> 6, ls = g & 63;
        const float* src = kb + (size_t)(ks * 16 + (ls >> 5) * 8) * NL + (ls & 31);
        half8 h;
        #pragma unroll
        for (int t = 0; t < 8; ++t) h[t] = (_Float16)src[(size_t)t * NL];
        *(half8*)(kF + g * 8) = h;
    }
}

__global__ __launch_bounds__(256, 2)
void att_mfma6(const float* __restrict__ q,
               const float* __restrict__ kk,
               const float* __restrict__ v,
               const float* __restrict__ sd,
               const float* __restrict__ bt,
               const int* __restrict__ ri,
               float* __restrict__ out)
{
    (void)ri;   // rel_index is analytic: (yi-yj+31)*63 + (xi-xj+31)
    __shared__ __align__(16) char smem[SMEM_B];
    _Float16* kF   = (_Float16*)(smem + OFF_K);
    _Float16* vF   = (_Float16*)(smem + OFF_V);
    _Float16* sF   = (_Float16*)(smem + OFF_S);
    float*    pS   = (float*)(smem + OFF_PS);
    _Float16* pB   = (_Float16*)(smem + OFF_PB);
    float*    mrow = (float*)(smem + OFF_ROWS);
    float*    lrow = mrow + 32;
    float*    arow = mrow + 64;

    const int tid  = threadIdx.x;
    const int lane = tid & 63;
    const int wv   = tid >> 6;

    // XCD-locality swizzle: one batch's 32 i-blocks cluster on one XCD.
    const int bid = blockIdx.x;
    const int b   = (bid & 7) + ((bid >> 8) << 3);
    const int ib  = (bid >> 3) & 31;
    const int i0  = ib * MI;

    const float* kbase = kk + (size_t)b * NC * NL;
    const float* vbase = v  + (size_t)b * NC * NL;
    const float* sbase = sd + (size_t)b * NC * NL;

    // ---- Q A-fragments (hi/lo fp16), waves 0,1 only: kh = wv, ks = wv*8+kk2 ----
    half8 qhi[8], qlo[8];
    if (wv < 2) {
        const float* qb = q + (size_t)b * NC * NL + i0 + (lane & 31);
        #pragma unroll
        for (int kk2 = 0; kk2 < 8; ++kk2) {
            const int c0 = (wv * 8 + kk2) * 16 + (lane >> 5) * 8;
            #pragma unroll
            for (int t = 0; t < 8; ++t) {
                float x = qb[(size_t)(c0 + t) * NL];
                _Float16 h = (_Float16)x;
                qhi[kk2][t] = h;
                qlo[kk2][t] = (_Float16)(x - (float)h);
            }
        }
    }
    if (tid < 32) { mrow[tid] = -1e30f; lrow[tid] = 0.0f; arow[tid] = 1.0f; }

    // ---- staging geometry (V/SD): coalesced global reads, swizzled b128 frag writes
    int co[4], swg[4];
    #pragma unroll
    for (int r = 0; r < 4; ++r) {
        const int c = (tid >> 2) + r * 64, jc = tid & 3;
        co[r] = c * NL + jc * 8;
        const int gr = ((c >> 5) * 2 + (jc >> 1)) * 64 + (jc & 1) * 32 + (c & 31);
        swg[r] = swz(gr) * 8;
    }
    // PV read offsets (half units), swizzled, loop-invariant
    int gA[2][2];
    #pragma unroll
    for (int d = 0; d < 2; ++d) {
        const int ct = wv * 2 + d;
        gA[d][0] = swz(ct * 128 + lane) * 8;
        gA[d][1] = swz(ct * 128 + 64 + lane) * 8;
    }

    floatx16 aV[2], aS[2];
    #pragma unroll
    for (int d = 0; d < 2; ++d)
        #pragma unroll
        for (int r = 0; r < 16; ++r) { aV[d][r] = 0.f; aS[d][r] = 0.f; }

    auto pv_step = [&]() {
        const float al = arow[lane & 31];
        if (!__all(al == 1.0f)) {   // exact: skip is bitwise-identical when max unchanged
            #pragma unroll
            for (int d = 0; d < 2; ++d)
                #pragma unroll
                for (int r = 0; r < 16; ++r) { aV[d][r] *= al; aS[d][r] *= al; }
        }
        half8 pb0 = *(const half8*)(pB + lane * 8);
        half8 pb1 = *(const half8*)(pB + (64 + lane) * 8);
        #pragma unroll
        for (int d = 0; d < 2; ++d) {
            half8 a0 = *(const half8*)(vF + gA[d][0]);
            half8 a1 = *(const half8*)(vF + gA[d][1]);
            aV[d] = MFMA(a0, pb0, aV[d]);
            aV[d] = MFMA(a1, pb1, aV[d]);
            half8 b0 = *(const half8*)(sF + gA[d][0]);
            half8 b1 = *(const half8*)(sF + gA[d][1]);
            aS[d] = MFMA(b0, pb0, aS[d]);
            aS[d] = MFMA(b1, pb1, aS[d]);
        }
    };

    stage_k(kF, kbase, tid);       // kF(0)
    __syncthreads();

    for (int it = 0; it < NIT; ++it) {
        const int j0 = it * BJ;

        // ---- T14: issue V/SD stage loads NOW; results consumed after B1.
        // Latency hides under PV + scores. 64 VGPR held across the phase.
        float4 vp0[4], vp1[4], sp0[4], sp1[4];
        #pragma unroll
        for (int r = 0; r < 4; ++r) {
            const float* vs = vbase + co[r] + j0;
            vp0[r] = *(const float4*)(vs);
            vp1[r] = *(const float4*)(vs + 4);
            const float* ss = sbase + co[r] + j0;
            sp0[r] = *(const float4*)(ss);
            sp1[r] = *(const float4*)(ss + 4);
        }

        // ---- PV(it-1): all waves, 2 c-tiles each ----
        if (it > 0) pv_step();

        // ---- scores(it): waves 0,1 (kh = wv), TWO independent MFMA chains (hi/lo) ----
        if (wv < 2) {
            floatx16 Sh, Sl;
            #pragma unroll
            for (int r = 0; r < 16; ++r) { Sh[r] = 0.f; Sl[r] = 0.f; }
            #pragma unroll
            for (int kk2 = 0; kk2 < 8; ++kk2) {
                const int ks = wv * 8 + kk2;
                half8 bf = *(const half8*)(kF + (ks * 64 + lane) * 8);
                Sh = MFMA(qhi[kk2], bf, Sh);
                Sl = MFMA(qlo[kk2], bf, Sl);
            }
            float* ps = pS + wv * 32 * PSP + (lane & 31);
            #pragma unroll
            for (int r = 0; r < 16; ++r) {
                int row = (r & 3) + 8 * (r >> 2) + 4 * (lane >> 5);
                ps[row * PSP] = Sh[r] + Sl[r];
            }
        }
        __syncthreads();   // B1: pS ready; kF/vF/sF old reads done

        // ---- stage kF(it+1): loads issue first (latency covered by work below) ----
        if (it + 1 < NIT) stage_k(kF, kbase + j0 + BJ, tid);

        // ---- V/SD: cvt + swizzled write from prefetched regs (no load latency here) ----
        #pragma unroll
        for (int r = 0; r < 4; ++r) {
            half8 h;
            h[0] = (_Float16)vp0[r].x; h[1] = (_Float16)vp0[r].y;
            h[2] = (_Float16)vp0[r].z; h[3] = (_Float16)vp0[r].w;
            h[4] = (_Float16)vp1[r].x; h[5] = (_Float16)vp1[r].y;
            h[6] = (_Float16)vp1[r].z; h[7] = (_Float16)vp1[r].w;
            *(half8*)(vF + swg[r]) = h;
        }
        #pragma unroll
        for (int r = 0; r < 4; ++r) {
            half8 h;
            h[0] = (_Float16)sp0[r].x; h[1] = (_Float16)sp0[r].y;
            h[2] = (_Float16)sp0[r].z; h[3] = (_Float16)sp0[r].w;
            h[4] = (_Float16)sp1[r].x; h[5] = (_Float16)sp1[r].y;
            h[6] = (_Float16)sp1[r].z; h[7] = (_Float16)sp1[r].w;
            *(half8*)(sF + swg[r]) = h;
        }

        // ---- softmax(it): thread (i = tid>>3, s = tid&7) owns 4 cols ----
        {
            const int i = tid >> 3, s = tid & 7;
            const float* ps0 = pS + i * PSP + s * 4;
            // analytic bias: idx(x) = (ib-it+31)*63 + (i-(4s+x)+31) -> reverse-consecutive
            const float* bp = bt + (ib - it + 31) * 63 + (i - 4 * s + 28);
            float sc[4];
            sc[0] = ps0[0] + ps0[32 * PSP + 0] + bp[3];
            sc[1] = ps0[1] + ps0[32 * PSP + 1] + bp[2];
            sc[2] = ps0[2] + ps0[32 * PSP + 2] + bp[1];
            sc[3] = ps0[3] + ps0[32 * PSP + 3] + bp[0];
            float lm = fmaxf(fmaxf(sc[0], sc[1]), fmaxf(sc[2], sc[3]));
            lm = fmaxf(lm, __shfl_xor(lm, 1));
            lm = fmaxf(lm, __shfl_xor(lm, 2));
            lm = fmaxf(lm, __shfl_xor(lm, 4));
            const float mo = mrow[i];
            const float mn = fmaxf(lm, mo);
            float sum = 0.f;
            half4 ph;
            #pragma unroll
            for (int x = 0; x < 4; ++x) {
                float e = __expf(sc[x] - mn);
                sum += e;
                ph[x] = (_Float16)e;
            }
            sum += __shfl_xor(sum, 1);
            sum += __shfl_xor(sum, 2);
            sum += __shfl_xor(sum, 4);
            // pB frag: B[k=j][n=i], j = 4s..4s+3 -> ksj=s>>2, half=(s>>1)&1, t0=(s&1)*4
            *(half4*)(pB + (((s >> 2) * 64) + ((s >> 1) & 1) * 32 + i) * 8 + (s & 1) * 4) = ph;
            if (s == 0) {
                float al = __expf(mo - mn);   // == 1.0f exactly when mn == mo
                arow[i] = al;
                lrow[i] = lrow[i] * al + sum;
                mrow[i] = mn;
            }
        }
        __syncthreads();   // B2: pB/rows/kF(it+1)/vF/sF(it) ready
    }

    // ---- drain PV(NIT-1) ----
    pv_step();

    // ---- epilogue: normalize, LDS transpose (scr overlaps dead kF/vF), coalesced store ----
    const float linv = 1.0f / lrow[lane & 31];
    float* scr = (float*)smem;   // 256*33*4 = 33792 B
    __syncthreads();
    #pragma unroll
    for (int d = 0; d < 2; ++d) {
        const int ct = wv * 2 + d;
        #pragma unroll
        for (int r = 0; r < 16; ++r) {
            int c = ct * 32 + (r & 3) + 8 * (r >> 2) + 4 * (lane >> 5);
            scr[c * 33 + (lane & 31)] = aV[d][r] * linv;
        }
    }
    __syncthreads();
    {
        float* og = out + ((size_t)b * NC + tid) * NL + i0;
        #pragma unroll
        for (int g = 0; g < 8; ++g) {
            float4 o;
            o.x = scr[tid * 33 + g * 4 + 0];
            o.y = scr[tid * 33 + g * 4 + 1];
            o.z = scr[tid * 33 + g * 4 + 2];
            o.w = scr[tid * 33 + g * 4 + 3];
            *(float4*)(og + g * 4) = o;
        }
    }
    __syncthreads();
    #pragma unroll
    for (int d = 0; d < 2; ++d) {
        const int ct = wv * 2 + d;
        #pragma unroll
        for (int r = 0; r < 16; ++r) {
            int c = ct * 32 + (r & 3) + 8 * (r >> 2) + 4 * (lane >> 5);
            scr[c * 33 + (lane & 31)] = aS[d][r] * linv;
        }
    }
    __syncthreads();
    {
        float* og = out + (size_t)NB * NC * NL + ((size_t)b * NC + tid) * NL + i0;
        #pragma unroll
        for (int g = 0; g < 8; ++g) {
            float4 o;
            o.x = scr[tid * 33 + g * 4 + 0];
            o.y = scr[tid * 33 + g * 4 + 1];
            o.z = scr[tid * 33 + g * 4 + 2];
            o.w = scr[tid * 33 + g * 4 + 3];
            *(float4*)(og + g * 4) = o;
        }
    }
}

extern "C" void kernel_launch(void* const* d_in, const int* in_sizes, int n_in,
                              void* d_out, int out_size, void* d_ws, size_t ws_size,
                              hipStream_t stream)
{
    (void)in_sizes; (void)n_in; (void)d_ws; (void)ws_size; (void)out_size;
    const float* q  = (const float*)d_in[0];
    const float* k  = (const float*)d_in[1];
    const float* v  = (const float*)d_in[2];
    const float* s  = (const float*)d_in[3];
    const float* bt = (const float*)d_in[4];
    const int*   ri = (const int*)d_in[5];
    att_mfma6<<<dim3(NB * (NL / MI)), dim3(256), 0, stream>>>(
        q, k, v, s, bt, ri, (float*)d_out);
}

// Round 6
// 398.192 us; speedup vs baseline: 1.5000x; 1.5000x over previous
//
#include <hip/hip_runtime.h>

typedef _Float16 half8 __attribute__((ext_vector_type(8)));
typedef _Float16 half4 __attribute__((ext_vector_type(4)));
typedef float    floatx16 __attribute__((ext_vector_type(16)));

#define MFMA(a, b, c) __builtin_amdgcn_mfma_f32_32x32x16_f16((a), (b), (c), 0, 0, 0)

constexpr int NB = 32, NC = 256, NL = 1024, MI = 32, BJ = 32;
constexpr int NIT = NL / BJ;   // 32
constexpr int PSP = 33;        // f32 hi-partial pitch (floats)
constexpr int PSL = 36;        // f16 lo-partial pitch (halves): 72B rows -> 8B-aligned half4 reads

// LDS byte offsets (total 64640 <= 64KB static, launch_bounds(256,2) -> 2 blocks/CU)
constexpr int OFF_K    = 0;        // kF  f16 [16 ks][64 ls][8 t] = 16384
constexpr int OFF_V    = 16384;    // vF  f16 [8 ct][2 ksj][64 ls][8 t] = 16384 (swizzled granules)
constexpr int OFF_S    = 32768;    // sF  same = 16384
constexpr int OFF_PS   = 49152;    // pS  f32 [2 kh][32 i][33] = 8448   (hi partials, waves 0,1)
constexpr int OFF_PL   = 57600;    // pL  f16 [2 kh][32 i][36] = 4608   (lo partials, waves 2,3)
constexpr int OFF_PB   = 62208;    // pB  f16 [2 ksj][64 ls][8 t] = 2048
constexpr int OFF_ROWS = 64256;    // m/l/a rows 3*32*4 = 384
constexpr int SMEM_B   = 64640;

// Granule swizzle for vF/sF: XOR bits 5-6 of the granule index into bits 1-2 so the
// 4 jc-variants of one c-row land in different bank quads. Involution; write AND read.
__device__ __forceinline__ int swz(int g) { return g ^ (((g >> 5) & 3) << 1); }

// K staging: coalesced global reads (lanes sweep j), b128 frag writes.
__device__ __forceinline__ void stage_k(_Float16* kF, const float* kb, int tid) {
    #pragma unroll
    for (int r = 0; r < 4; ++r) {
        const int g = tid + r * 256, ks = g >> 6, ls = g & 63;
        const float* src = kb + (size_t)(ks * 16 + (ls >> 5) * 8) * NL + (ls & 31);
        half8 h;
        #pragma unroll
        for (int t = 0; t < 8; ++t) h[t] = (_Float16)src[(size_t)t * NL];
        *(half8*)(kF + g * 8) = h;
    }
}

// v/std staging: coalesced global reads (4 lanes per c-row), SWIZZLED b128 frag writes.
__device__ __forceinline__ void stage_a(_Float16* dst, const float* base, int tid) {
    #pragma unroll
    for (int r = 0; r < 4; ++r) {
        const int c = (tid >> 2) + r * 64, jc = tid & 3;
        const float* src = base + (size_t)c * NL + jc * 8;
        float4 a = *(const float4*)src;
        float4 b = *(const float4*)(src + 4);
        half8 h;
        h[0] = (_Float16)a.x; h[1] = (_Float16)a.y; h[2] = (_Float16)a.z; h[3] = (_Float16)a.w;
        h[4] = (_Float16)b.x; h[5] = (_Float16)b.y; h[6] = (_Float16)b.z; h[7] = (_Float16)b.w;
        const int gr = ((c >> 5) * 2 + (jc >> 1)) * 64 + (jc & 1) * 32 + (c & 31);
        *(half8*)(dst + swz(gr) * 8) = h;
    }
}

__global__ __launch_bounds__(256, 2)
void att_mfma7(const float* __restrict__ q,
               const float* __restrict__ kk,
               const float* __restrict__ v,
               const float* __restrict__ sd,
               const float* __restrict__ bt,
               const int* __restrict__ ri,
               float* __restrict__ out)
{
    (void)ri;   // rel_index is analytic: (yi-yj+31)*63 + (xi-xj+31)
    __shared__ __align__(16) char smem[SMEM_B];
    _Float16* kF   = (_Float16*)(smem + OFF_K);
    _Float16* vF   = (_Float16*)(smem + OFF_V);
    _Float16* sF   = (_Float16*)(smem + OFF_S);
    float*    pS   = (float*)(smem + OFF_PS);
    _Float16* pL   = (_Float16*)(smem + OFF_PL);
    _Float16* pB   = (_Float16*)(smem + OFF_PB);
    float*    mrow = (float*)(smem + OFF_ROWS);
    float*    lrow = mrow + 32;
    float*    arow = mrow + 64;

    const int tid  = threadIdx.x;
    const int lane = tid & 63;
    const int wv   = tid >> 6;

    // XCD-locality swizzle: one batch's 32 i-blocks cluster on one XCD.
    const int bid = blockIdx.x;
    const int b   = (bid & 7) + ((bid >> 8) << 3);
    const int ib  = (bid >> 3) & 31;
    const int i0  = ib * MI;

    const float* kbase = kk + (size_t)b * NC * NL;
    const float* vbase = v  + (size_t)b * NC * NL;
    const float* sbase = sd + (size_t)b * NC * NL;

    // ---- Q A-fragments: 4-way score split.
    // waves 0,1 hold HI frags for kh = wv; waves 2,3 hold LO frags for kh = wv-2.
    // Each wave holds only 8 half8 (32 VGPR) -- half of R3's critical-wave load.
    half8 qf[8];
    {
        const float* qb = q + (size_t)b * NC * NL + i0 + (lane & 31);
        const int kh = wv & 1;
        #pragma unroll
        for (int kk2 = 0; kk2 < 8; ++kk2) {
            const int c0 = (kh * 8 + kk2) * 16 + (lane >> 5) * 8;
            #pragma unroll
            for (int t = 0; t < 8; ++t) {
                float x = qb[(size_t)(c0 + t) * NL];
                _Float16 h = (_Float16)x;
                qf[kk2][t] = (wv < 2) ? h : (_Float16)(x - (float)h);
            }
        }
    }
    if (tid < 32) { mrow[tid] = -1e30f; lrow[tid] = 0.0f; arow[tid] = 1.0f; }

    // PV read offsets (half units), swizzled, loop-invariant
    int gA[2][2];
    #pragma unroll
    for (int d = 0; d < 2; ++d) {
        const int ct = wv * 2 + d;
        gA[d][0] = swz(ct * 128 + lane) * 8;
        gA[d][1] = swz(ct * 128 + 64 + lane) * 8;
    }

    floatx16 aV[2], aS[2];
    #pragma unroll
    for (int d = 0; d < 2; ++d)
        #pragma unroll
        for (int r = 0; r < 16; ++r) { aV[d][r] = 0.f; aS[d][r] = 0.f; }

    auto pv_step = [&]() {
        const float al = arow[lane & 31];
        if (!__all(al == 1.0f)) {   // exact: skip is bitwise-identical when max unchanged
            #pragma unroll
            for (int d = 0; d < 2; ++d)
                #pragma unroll
                for (int r = 0; r < 16; ++r) { aV[d][r] *= al; aS[d][r] *= al; }
        }
        half8 pb0 = *(const half8*)(pB + lane * 8);
        half8 pb1 = *(const half8*)(pB + (64 + lane) * 8);
        #pragma unroll
        for (int d = 0; d < 2; ++d) {
            half8 a0 = *(const half8*)(vF + gA[d][0]);
            half8 a1 = *(const half8*)(vF + gA[d][1]);
            aV[d] = MFMA(a0, pb0, aV[d]);
            aV[d] = MFMA(a1, pb1, aV[d]);
            half8 b0 = *(const half8*)(sF + gA[d][0]);
            half8 b1 = *(const half8*)(sF + gA[d][1]);
            aS[d] = MFMA(b0, pb0, aS[d]);
            aS[d] = MFMA(b1, pb1, aS[d]);
        }
    };

    stage_k(kF, kbase, tid);       // kF(0)
    __syncthreads();

    for (int it = 0; it < NIT; ++it) {
        const int j0 = it * BJ;

        // ---- PV(it-1): all waves, 2 c-tiles each ----
        if (it > 0) pv_step();

        // ---- scores(it): ALL 4 waves, 8-deep chain each.
        // waves 0,1: hi partials (f32 -> pS); waves 2,3: lo partials (tiny, f16 -> pL).
        {
            floatx16 S;
            #pragma unroll
            for (int r = 0; r < 16; ++r) S[r] = 0.f;
            const int kh = wv & 1;
            #pragma unroll
            for (int kk2 = 0; kk2 < 8; ++kk2) {
                half8 bf = *(const half8*)(kF + ((kh * 8 + kk2) * 64 + lane) * 8);
                S = MFMA(qf[kk2], bf, S);
            }
            if (wv < 2) {
                float* ps = pS + kh * 32 * PSP + (lane & 31);
                #pragma unroll
                for (int r = 0; r < 16; ++r) {
                    int row = (r & 3) + 8 * (r >> 2) + 4 * (lane >> 5);
                    ps[row * PSP] = S[r];
                }
            } else {
                _Float16* pl = pL + kh * 32 * PSL + (lane & 31);
                #pragma unroll
                for (int r = 0; r < 16; ++r) {
                    int row = (r & 3) + 8 * (r >> 2) + 4 * (lane >> 5);
                    pl[row * PSL] = (_Float16)S[r];
                }
            }
        }
        __syncthreads();   // B1: pS/pL ready; kF/vF/sF old reads done

        // ---- stage kF(it+1), vF/sF(it) ----
        if (it + 1 < NIT) stage_k(kF, kbase + j0 + BJ, tid);
        stage_a(vF, vbase + j0, tid);
        stage_a(sF, sbase + j0, tid);

        // ---- softmax(it): thread (i = tid>>3, s = tid&7) owns 4 cols ----
        {
            const int i = tid >> 3, s = tid & 7;
            const float* ps0 = pS + i * PSP + s * 4;
            const _Float16* lp = pL + i * PSL + s * 4;
            const half4 l0 = *(const half4*)(lp);
            const half4 l1 = *(const half4*)(lp + 32 * PSL);
            // analytic bias: idx(x) = (ib-it+31)*63 + (i-(4s+x)+31) -> reverse-consecutive
            const float* bp = bt + (ib - it + 31) * 63 + (i - 4 * s + 28);
            float sc[4];
            sc[0] = ps0[0] + ps0[32 * PSP + 0] + (float)l0[0] + (float)l1[0] + bp[3];
            sc[1] = ps0[1] + ps0[32 * PSP + 1] + (float)l0[1] + (float)l1[1] + bp[2];
            sc[2] = ps0[2] + ps0[32 * PSP + 2] + (float)l0[2] + (float)l1[2] + bp[1];
            sc[3] = ps0[3] + ps0[32 * PSP + 3] + (float)l0[3] + (float)l1[3] + bp[0];
            float lm = fmaxf(fmaxf(sc[0], sc[1]), fmaxf(sc[2], sc[3]));
            lm = fmaxf(lm, __shfl_xor(lm, 1));
            lm = fmaxf(lm, __shfl_xor(lm, 2));
            lm = fmaxf(lm, __shfl_xor(lm, 4));
            const float mo = mrow[i];
            const float mn = fmaxf(lm, mo);
            float sum = 0.f;
            half4 ph;
            #pragma unroll
            for (int x = 0; x < 4; ++x) {
                float e = __expf(sc[x] - mn);
                sum += e;
                ph[x] = (_Float16)e;
            }
            sum += __shfl_xor(sum, 1);
            sum += __shfl_xor(sum, 2);
            sum += __shfl_xor(sum, 4);
            // pB frag: B[k=j][n=i], j = 4s..4s+3 -> ksj=s>>2, half=(s>>1)&1, t0=(s&1)*4
            *(half4*)(pB + (((s >> 2) * 64) + ((s >> 1) & 1) * 32 + i) * 8 + (s & 1) * 4) = ph;
            if (s == 0) {
                float al = __expf(mo - mn);   // == 1.0f exactly when mn == mo
                arow[i] = al;
                lrow[i] = lrow[i] * al + sum;
                mrow[i] = mn;
            }
        }
        __syncthreads();   // B2: pB/rows/kF(it+1)/vF/sF(it) ready
    }

    // ---- drain PV(NIT-1) ----
    pv_step();

    // ---- epilogue: normalize, LDS transpose (scr overlaps dead kF/vF), coalesced store ----
    const float linv = 1.0f / lrow[lane & 31];
    float* scr = (float*)smem;   // 256*33*4 = 33792 B (< OFF_PB; rows untouched)
    __syncthreads();
    #pragma unroll
    for (int d = 0; d < 2; ++d) {
        const int ct = wv * 2 + d;
        #pragma unroll
        for (int r = 0; r < 16; ++r) {
            int c = ct * 32 + (r & 3) + 8 * (r >> 2) + 4 * (lane >> 5);
            scr[c * 33 + (lane & 31)] = aV[d][r] * linv;
        }
    }
    __syncthreads();
    {
        float* og = out + ((size_t)b * NC + tid) * NL + i0;
        #pragma unroll
        for (int g = 0; g < 8; ++g) {
            float4 o;
            o.x = scr[tid * 33 + g * 4 + 0];
            o.y = scr[tid * 33 + g * 4 + 1];
            o.z = scr[tid * 33 + g * 4 + 2];
            o.w = scr[tid * 33 + g * 4 + 3];
            *(float4*)(og + g * 4) = o;
        }
    }
    __syncthreads();
    #pragma unroll
    for (int d = 0; d < 2; ++d) {
        const int ct = wv * 2 + d;
        #pragma unroll
        for (int r = 0; r < 16; ++r) {
            int c = ct * 32 + (r & 3) + 8 * (r >> 2) + 4 * (lane >> 5);
            scr[c * 33 + (lane & 31)] = aS[d][r] * linv;
        }
    }
    __syncthreads();
    {
        float* og = out + (size_t)NB * NC * NL + ((size_t)b * NC + tid) * NL + i0;
        #pragma unroll
        for (int g = 0; g < 8; ++g) {
            float4 o;
            o.x = scr[tid * 33 + g * 4 + 0];
            o.y = scr[tid * 33 + g * 4 + 1];
            o.z = scr[tid * 33 + g * 4 + 2];
            o.w = scr[tid * 33 + g * 4 + 3];
            *(float4*)(og + g * 4) = o;
        }
    }
}

extern "C" void kernel_launch(void* const* d_in, const int* in_sizes, int n_in,
                              void* d_out, int out_size, void* d_ws, size_t ws_size,
                              hipStream_t stream)
{
    (void)in_sizes; (void)n_in; (void)d_ws; (void)ws_size; (void)out_size;
    const float* q  = (const float*)d_in[0];
    const float* k  = (const float*)d_in[1];
    const float* v  = (const float*)d_in[2];
    const float* s  = (const float*)d_in[3];
    const float* bt = (const float*)d_in[4];
    const int*   ri = (const int*)d_in[5];
    att_mfma7<<<dim3(NB * (NL / MI)), dim3(256), 0, stream>>>(
        q, k, v, s, bt, ri, (float*)d_out);
}